// Round 9
// baseline (634.544 us; speedup 1.0000x reference)
//
#include <hip/hip_runtime.h>
#include <hip/hip_bf16.h>

#define NB 2048      // batches
#define NP 32        // particles per batch
#define ND 6         // action dim
#define NOBS 17      // obs dim
#define NH 256       // hidden
#define NSTEPS 10
#define C_LR 0.1f
#define C_LIM 1.0f
#define C_LOGNP1 3.4965075614664802f   // float32(log(33))

typedef __bf16 bf16x8 __attribute__((ext_vector_type(8)));
typedef float  f32x4  __attribute__((ext_vector_type(4)));

#define MFMA(a, b, c) __builtin_amdgcn_mfma_f32_16x16x32_bf16(a, b, c, 0, 0, 0)

// fp32 -> bf16 bits, round-to-nearest-even (finite inputs)
static __device__ __forceinline__ unsigned short f2bf(float f) {
    union { float f; unsigned u; } c; c.f = f;
    const unsigned r = c.u + 0x7fffu + ((c.u >> 16) & 1u);
    return (unsigned short)(r >> 16);
}

// pack two fp32 -> two bf16 in one u32 (low = a). HW packed cvt if available.
static __device__ __forceinline__ unsigned pk2bf(float a, float b) {
#if __has_builtin(__builtin_amdgcn_cvt_pk_bf16_f32)
    auto p = __builtin_amdgcn_cvt_pk_bf16_f32(a, b);
    unsigned u; __builtin_memcpy(&u, &p, 4);
    return u;
#else
    return (unsigned)f2bf(a) | ((unsigned)f2bf(b) << 16);
#endif
}

// ---------------------------------------------------------------------------
// Prep: B-fragment-swizzled bf16 copies in d_ws (unchanged from R8).
//   ws[0      ..65535]  : W2    as B (fwd)
//   ws[65536  ..131071] : W2^T  as B (bwd)
//   ws[131072 ..135167] : W1x^T (256x16, cols>=6 zero) as B (score GEMM)
//   ws[135168 ..143359] : W1aug (32x256: rows 0..22 = W1, 23..31 = 0) as B
// ---------------------------------------------------------------------------
__global__ void prep_swizzle(const float* __restrict__ W1, const float* __restrict__ W2,
                             unsigned short* __restrict__ ws) {
    const int g = blockIdx.x * 256 + threadIdx.x;
    unsigned short v[8];
    if (g < 8192) {
        const int l = g & 63, fid = g >> 6;
        const int kt = fid >> 4, nt = fid & 15;
        const int row0 = kt * 32 + (l >> 4) * 8;
        const int col  = nt * 16 + (l & 15);
#pragma unroll
        for (int j = 0; j < 8; ++j) v[j] = f2bf(W2[(row0 + j) * NH + col]);
        ushort4* dst = (ushort4*)(ws + (size_t)g * 8);
        dst[0] = make_ushort4(v[0], v[1], v[2], v[3]);
        dst[1] = make_ushort4(v[4], v[5], v[6], v[7]);
    } else if (g < 16384) {
        const int e = g - 8192;
        const int l = e & 63, fid = e >> 6;
        const int kt = fid >> 4, nt = fid & 15;
        const int row  = nt * 16 + (l & 15);        // W2^T[k][n] = W2[n][k]
        const int col0 = kt * 32 + (l >> 4) * 8;
#pragma unroll
        for (int j = 0; j < 8; ++j) v[j] = f2bf(W2[row * NH + col0 + j]);
        ushort4* dst = (ushort4*)(ws + 65536 + (size_t)e * 8);
        dst[0] = make_ushort4(v[0], v[1], v[2], v[3]);
        dst[1] = make_ushort4(v[4], v[5], v[6], v[7]);
    } else if (g < 16896) {
        const int e = g - 16384;
        const int l = e & 63, kt = e >> 6;
        const int n  = l & 15;
        const int k0 = kt * 32 + (l >> 4) * 8;
#pragma unroll
        for (int j = 0; j < 8; ++j)
            v[j] = (n < ND) ? f2bf(W1[(NOBS + n) * NH + k0 + j]) : (unsigned short)0;
        ushort4* dst = (ushort4*)(ws + 131072 + (size_t)e * 8);
        dst[0] = make_ushort4(v[0], v[1], v[2], v[3]);
        dst[1] = make_ushort4(v[4], v[5], v[6], v[7]);
    } else if (g < 17920) {
        const int e = g - 16896;                    // 16 frags (nt) x 64 lanes
        const int l = e & 63, nt = e >> 6;
        const int col = nt * 16 + (l & 15);
        const int r0  = (l >> 4) * 8;
#pragma unroll
        for (int j = 0; j < 8; ++j)
            v[j] = (r0 + j < NOBS + ND) ? f2bf(W1[(r0 + j) * NH + col]) : (unsigned short)0;
        ushort4* dst = (ushort4*)(ws + 135168 + (size_t)e * 8);
        dst[0] = make_ushort4(v[0], v[1], v[2], v[3]);
        dst[1] = make_ushort4(v[4], v[5], v[6], v[7]);
    }
}

// ---------------------------------------------------------------------------
// Main kernel: one WG per TWO batches (M=64 GEMMs), 256 threads = 4 waves.
// Bank-conflict-free A-fragment LDS layout for 64x256 matrix M[s][c] (u16):
//   fid  = (c>>5)*4 + (s>>4)                      (1024 B per fragment)
//   addr = fid*512 + (s&3)*128 + (((c>>3)>>1)&1)*64 + ((s>>2)&3)*16
//          + ((c>>3)&1)*8 + (c&7)
// Writer (C-layout, fixed reg=s&3 per instr): banks = 8*quad + 4*b3 + (ln&7)/2
//   -> all 32 banks, 2 lanes/bank (free).  Reader: 16B at fid*512 + aoff(lane).
// ---------------------------------------------------------------------------
__global__ __launch_bounds__(256, 4)
void svgd_kernel(const float* __restrict__ obs, const float* __restrict__ a_in,
                 const float* __restrict__ W1, const float* __restrict__ b1,
                 const float* __restrict__ W2, const float* __restrict__ b2,
                 const float* __restrict__ W3, const unsigned short* __restrict__ ws,
                 float* __restrict__ out)
{
    __shared__ __attribute__((aligned(16))) unsigned short hA[64 * NH]; // 32KB h1 -> dh2 -> masked dh1
    __shared__ float Xs[2][384];        // 3KB double-buffered X, stride 6
    __shared__ float sc_[512];          // 2KB score, stride 8
    __shared__ float med_s[2];
    // total ~37.4KB -> 4 WGs/CU

    const int t    = threadIdx.x;
    const int bb   = blockIdx.x;        // batches 2bb, 2bb+1
    const int lane = t & 63;
    const int wid  = t >> 6;
    const int w4   = wid * 4;           // this wave's first nt (GEMM N-split)
    const int quad = lane >> 4;
    const int ln15 = lane & 15;
    const int qo = t >> 7, iao = (t & 127) >> 2, jgo = t & 3;

    // de-phase co-resident WGs (residency slot ~ bb>>8): ~4.3us per slot
    {
        const int slot = (bb >> 8) & 3;
        for (int i = 0; i < slot * 20; ++i) __builtin_amdgcn_s_sleep(8);
    }

    const unsigned short* gW2f = ws;
    const unsigned short* gW2b = ws + 65536;
    const unsigned short* gW1p = ws + 131072;
    const unsigned short* gW1f = ws + 135168;

    // per-lane A-read offset into a fragment (u16 units)
    const int aoff = (lane & 3) * 128 + (lane >> 5) * 64
                   + ((lane >> 2) & 3) * 16 + ((lane >> 4) & 1) * 8;
    // per-q epilogue write base (u16 units); writes go at kqb[q] + m*512 + reg*128
    int kqb[4];
#pragma unroll
    for (int q = 0; q < 4; ++q) {
        const int nt = w4 + q;
        kqb[q] = (nt >> 1) * 2048 + (nt & 1) * 64 + quad * 16
               + (ln15 >> 3) * 8 + (ln15 & 7);
    }

    // ---- init: obs -> hA scratch (coalesced), X -> Xs[0] ----
    {
        float* scr = (float*)hA;
        const float* obs_g = obs + (size_t)bb * 1088;
        for (int p = t; p < 1088; p += 256) scr[p] = obs_g[p];
        const float* a_g = a_in + (size_t)bb * 384;
        for (int p = t; p < 384; p += 256) Xs[0][p] = a_g[p];
    }
    __syncthreads();
    // a0: A-fragments of [obs|X|0] (64 rows x K=32) in registers, all 4 waves
    bf16x8 a0[4];
    {
        const float* scr = (const float*)hA;
#pragma unroll
        for (int m = 0; m < 4; ++m) {
            const int s = m * 16 + ln15;
#pragma unroll
            for (int j = 0; j < 8; ++j) {
                const int k = quad * 8 + j;
                float v = 0.0f;
                if (k < NOBS) v = scr[s * NOBS + k];
                else if (k < NOBS + ND) v = Xs[0][s * 6 + (k - NOBS)];
                a0[m][j] = (__bf16)v;
            }
        }
    }
    __syncthreads();   // scr reads done before step-0 P0 writes hA

    // ---- persistent per-thread scalars ----
    float b1r[4], b2r[4]; unsigned short w3u[4];
#pragma unroll
    for (int q = 0; q < 4; ++q) {
        const int n = (w4 + q) * 16 + ln15;
        b1r[q] = b1[n]; b2r[q] = b2[n]; w3u[q] = f2bf(W3[n]);
    }

    float logp_r = 0.0f;                // owned by jgo==3 threads
    int cur = 0;
    const f32x4 zv = {0.f, 0.f, 0.f, 0.f};

    for (int step = 0; step < NSTEPS; ++step) {
        // ---- P0: h1 = relu([obs|X] @ W1aug + b1), bias in C-operand ----
        unsigned msk[2] = {0u, 0u};     // h1>0 mask, bit = (q&1)*16 + m*4 + reg
        {
            bf16x8 w1B[4];
#pragma unroll
            for (int q = 0; q < 4; ++q)
                w1B[q] = *(const bf16x8*)(gW1f + ((w4 + q) * 64 + lane) * 8);
            f32x4 acc0[4][4];
#pragma unroll
            for (int m = 0; m < 4; ++m)
#pragma unroll
                for (int q = 0; q < 4; ++q) {
                    const f32x4 cb = {b1r[q], b1r[q], b1r[q], b1r[q]};
                    acc0[m][q] = MFMA(a0[m], w1B[q], cb);
                }
#pragma unroll
            for (int q = 0; q < 4; ++q) {
                const int kq = kqb[q];
#pragma unroll
                for (int m = 0; m < 4; ++m) {
                    const f32x4 v = acc0[m][q];
                    const unsigned p01 = pk2bf(fmaxf(v[0], 0.f), fmaxf(v[1], 0.f));
                    const unsigned p23 = pk2bf(fmaxf(v[2], 0.f), fmaxf(v[3], 0.f));
                    unsigned short* bp = &hA[kq + m * 512];
                    bp[0]   = (unsigned short)p01;
                    bp[128] = (unsigned short)(p01 >> 16);
                    bp[256] = (unsigned short)p23;
                    bp[384] = (unsigned short)(p23 >> 16);
                    const unsigned mm = (v[0] > 0.f ? 1u : 0u) | (v[1] > 0.f ? 2u : 0u)
                                      | (v[2] > 0.f ? 4u : 0u) | (v[3] > 0.f ? 8u : 0u);
                    msk[q >> 1] |= mm << ((q & 1) * 16 + m * 4);
                }
            }
        }
        __syncthreads();  // S1

        // ---- P2: fwd GEMM h2_pre = h1 @ W2, bias in C-init ----
        {
            f32x4 acc[4][4];
#pragma unroll
            for (int m = 0; m < 4; ++m)
#pragma unroll
                for (int q = 0; q < 4; ++q) {
                    const f32x4 cb = {b2r[q], b2r[q], b2r[q], b2r[q]};
                    acc[m][q] = cb;
                }
#pragma unroll 2
            for (int kt = 0; kt < 8; ++kt) {
                bf16x8 a[4];
#pragma unroll
                for (int m = 0; m < 4; ++m)
                    a[m] = *(const bf16x8*)&hA[(kt * 4 + m) * 512 + aoff];
#pragma unroll
                for (int q = 0; q < 4; ++q) {
                    const bf16x8 bf = *(const bf16x8*)(gW2f + ((kt * 16 + w4 + q) * 64 + lane) * 8);
#pragma unroll
                    for (int m = 0; m < 4; ++m) acc[m][q] = MFMA(a[m], bf, acc[m][q]);
                }
            }
            __syncthreads();  // S2: all h1 reads done
            // epilogue: dh2 = (h2_pre > 0) ? W3 : 0
#pragma unroll
            for (int q = 0; q < 4; ++q) {
                const int kq = kqb[q];
                const unsigned short w3v = w3u[q];
#pragma unroll
                for (int m = 0; m < 4; ++m) {
                    const f32x4 v = acc[m][q];
                    unsigned short* bp = &hA[kq + m * 512];
                    bp[0]   = v[0] > 0.f ? w3v : (unsigned short)0;
                    bp[128] = v[1] > 0.f ? w3v : (unsigned short)0;
                    bp[256] = v[2] > 0.f ? w3v : (unsigned short)0;
                    bp[384] = v[3] > 0.f ? w3v : (unsigned short)0;
                }
            }
        }
        __syncthreads();  // S3: dh2 visible

        // ---- P3: bwd GEMM dh1 = dh2 @ W2^T ----
        {
            f32x4 acc2[4][4];
#pragma unroll
            for (int m = 0; m < 4; ++m)
#pragma unroll
                for (int q = 0; q < 4; ++q) acc2[m][q] = zv;
#pragma unroll 2
            for (int kt = 0; kt < 8; ++kt) {
                bf16x8 a[4];
#pragma unroll
                for (int m = 0; m < 4; ++m)
                    a[m] = *(const bf16x8*)&hA[(kt * 4 + m) * 512 + aoff];
#pragma unroll
                for (int q = 0; q < 4; ++q) {
                    const bf16x8 bf = *(const bf16x8*)(gW2b + ((kt * 16 + w4 + q) * 64 + lane) * 8);
#pragma unroll
                    for (int m = 0; m < 4; ++m) acc2[m][q] = MFMA(a[m], bf, acc2[m][q]);
                }
            }
            __syncthreads();  // S4: all dh2 reads done
            // epilogue: masked dh1 from u32 bitmasks, packed bf16 convert
#pragma unroll
            for (int q = 0; q < 4; ++q) {
                const int kq = kqb[q];
                const unsigned ma = msk[q >> 1];
#pragma unroll
                for (int m = 0; m < 4; ++m) {
                    const f32x4 v = acc2[m][q];
                    const int b0 = (q & 1) * 16 + m * 4;
                    const float t0 = (ma & (1u << (b0 + 0))) ? v[0] : 0.f;
                    const float t1 = (ma & (1u << (b0 + 1))) ? v[1] : 0.f;
                    const float t2 = (ma & (1u << (b0 + 2))) ? v[2] : 0.f;
                    const float t3 = (ma & (1u << (b0 + 3))) ? v[3] : 0.f;
                    const unsigned p01 = pk2bf(t0, t1);
                    const unsigned p23 = pk2bf(t2, t3);
                    unsigned short* bp = &hA[kq + m * 512];
                    bp[0]   = (unsigned short)p01;
                    bp[128] = (unsigned short)(p01 >> 16);
                    bp[256] = (unsigned short)p23;
                    bp[384] = (unsigned short)(p23 >> 16);
                }
            }
        }
        __syncthreads();  // S5: masked dh1 visible

        // ---- P5: waves 2,3: score GEMM; waves 0,1: exact median ----
        if (wid >= 2) {
            const int mb = (wid - 2) * 2;
            f32x4 sa[2] = {zv, zv};
#pragma unroll
            for (int kt = 0; kt < 8; ++kt) {
                const bf16x8 bw = *(const bf16x8*)(gW1p + (kt * 64 + lane) * 8);
#pragma unroll
                for (int mm = 0; mm < 2; ++mm) {
                    const bf16x8 a = *(const bf16x8*)&hA[(kt * 4 + mb + mm) * 512 + aoff];
                    sa[mm] = MFMA(a, bw, sa[mm]);
                }
            }
            if (ln15 < ND) {
#pragma unroll
                for (int mm = 0; mm < 2; ++mm)
#pragma unroll
                    for (int reg = 0; reg < 4; ++reg)
                        sc_[((mb + mm) * 16 + quad * 4 + reg) * 8 + ln15] = sa[mm][reg];
            }
        } else {
            // rank-239 of 496 pair dists == rank-511 of full 1024 multiset (exact).
            const float* Xc = &Xs[cur][wid * 192];
            unsigned u[8];
#pragma unroll
            for (int r = 0; r < 8; ++r) {
                const int e = lane + 64 * r;
                if (e < 496) {
                    int i = (int)((63.0f - sqrtf(3969.0f - 8.0f * (float)e)) * 0.5f);
                    while (i * (63 - i) / 2 > e) --i;
                    while ((i + 1) * (62 - i) / 2 <= e) ++i;
                    const int j = i + 1 + (e - i * (63 - i) / 2);
                    float s = 0.f;
#pragma unroll
                    for (int d = 0; d < ND; ++d) {
                        const float df = Xc[i * 6 + d] - Xc[j * 6 + d];
                        s += df * df;
                    }
                    u[r] = __float_as_uint(s);
                } else u[r] = 0x7f800000u;
            }
            unsigned P = 0u;
            for (int bit = 30; bit >= 0; --bit) {
                const unsigned Q = P | (1u << bit);
                int c = 0;
#pragma unroll
                for (int r = 0; r < 8; ++r)
                    c += __popcll(__ballot(u[r] < Q));
                if (c <= 239) P = Q;
            }
            if (lane == 0) med_s[wid] = __uint_as_float(P);
        }
        __syncthreads();  // S6

        // ---- phi/l4/l5 partials; thread (batch qo, particle iao, 8 j's) ----
        {
            const int nxt = cur ^ 1;
            const float gam = 1.0f / (1e-8f + med_s[qo] / C_LOGNP1);
            const float* Xc = &Xs[cur][qo * 192];
            float xi[6];
#pragma unroll
            for (int d = 0; d < ND; ++d) xi[d] = Xc[iao * 6 + d];
            float w[8] = {0, 0, 0, 0, 0, 0, 0, 0};
#pragma unroll
            for (int jj = 0; jj < 8; ++jj) {
                const int j = jgo * 8 + jj;
                float df6[6], sj6[6];
                float dsv = 0.f, dot = 0.f;
#pragma unroll
                for (int d = 0; d < ND; ++d) {
                    df6[d] = xi[d] - Xc[j * 6 + d];
                    sj6[d] = sc_[(qo * 32 + j) * 8 + d];
                    dsv += df6[d] * df6[d];
                    dot += df6[d] * sj6[d];
                }
                const float kap = __expf(-gam * dsv);
                const float tg = 2.0f * gam * kap;
#pragma unroll
                for (int d = 0; d < ND; ++d) w[d] += kap * sj6[d] + tg * df6[d];
                w[6] -= tg * dot;                 // line_4 partial
                w[7] += tg * dsv - 6.0f * kap;    // line_5 partial (pre -2*gamma)
            }
#pragma unroll
            for (int off = 1; off < 4; off <<= 1)
#pragma unroll
                for (int c = 0; c < 8; ++c) w[c] += __shfl_xor(w[c], off);
            // commit to Xs[nxt] (disjoint buffer: no barrier vs phi reads)
            const int base = (qo * 32 + iao) * 6;
            {
                float x = xi[jgo] + C_LR * (w[jgo] * (1.0f / 32.0f));
                Xs[nxt][base + jgo] = fminf(fmaxf(x, -C_LIM), C_LIM);
            }
            if (jgo < 2) {
                const int d = jgo + 4;
                float x = xi[d] + C_LR * (w[d] * (1.0f / 32.0f));
                Xs[nxt][base + d] = fminf(fmaxf(x, -C_LIM), C_LIM);
            }
            if (jgo == 3)
                logp_r -= C_LR * (w[6] * (1.0f / 32.0f)
                                  - 2.0f * gam * (w[7] * (1.0f / 32.0f)));
        }
        __syncthreads();  // S7: new Xs visible

        // refresh a0 X-slots (k=17..22 -> j=1..6, quad 2 lanes hold them)
        cur ^= 1;
        if (quad == 2) {
#pragma unroll
            for (int m = 0; m < 4; ++m) {
                const int s = m * 16 + ln15;
#pragma unroll
                for (int j = 1; j <= 6; ++j)
                    a0[m][j] = (__bf16)Xs[cur][s * 6 + (j - 1)];
            }
        }
    }

    // ---- output: a (B*N, D) then logp (B, N) ----
    for (int p = t; p < 384; p += 256) out[(size_t)bb * 384 + p] = Xs[cur][p];
    if (jgo == 3) out[(size_t)NB * NP * ND + bb * 64 + qo * 32 + iao] = logp_r;
}

extern "C" void kernel_launch(void* const* d_in, const int* in_sizes, int n_in,
                              void* d_out, int out_size, void* d_ws, size_t ws_size,
                              hipStream_t stream) {
    const float* obs = (const float*)d_in[0];
    const float* a   = (const float*)d_in[1];
    const float* W1  = (const float*)d_in[2];
    const float* b1  = (const float*)d_in[3];
    const float* W2  = (const float*)d_in[4];
    const float* b2  = (const float*)d_in[5];
    const float* W3  = (const float*)d_in[6];
    // d_in[7] = b3: unused (constant offset drops out of grad; q-values never output)
    unsigned short* wsu = (unsigned short*)d_ws;   // needs 286720 bytes
    float* out = (float*)d_out;

    prep_swizzle<<<70, 256, 0, stream>>>(W1, W2, wsu);
    svgd_kernel<<<NB / 2, 256, 0, stream>>>(obs, a, W1, b1, W2, b2, W3, wsu, out);
}

// Round 10
// 518.479 us; speedup vs baseline: 1.2239x; 1.2239x over previous
//
#include <hip/hip_runtime.h>
#include <hip/hip_bf16.h>

#define NB 2048      // batches
#define NP 32        // particles per batch
#define ND 6         // action dim
#define NOBS 17      // obs dim
#define NH 256       // hidden
#define NSTEPS 10
#define C_LR 0.1f
#define C_LIM 1.0f
#define C_LOGNP1 3.4965075614664802f   // float32(log(33))

typedef __bf16 bf16x8 __attribute__((ext_vector_type(8)));
typedef float  f32x4  __attribute__((ext_vector_type(4)));

#define MFMA(a, b, c) __builtin_amdgcn_mfma_f32_16x16x32_bf16(a, b, c, 0, 0, 0)

// fp32 -> bf16 bits, round-to-nearest-even (finite inputs) — pure register ops
static __device__ __forceinline__ unsigned short f2bf(float f) {
    union { float f; unsigned u; } c; c.f = f;
    const unsigned r = c.u + 0x7fffu + ((c.u >> 16) & 1u);
    return (unsigned short)(r >> 16);
}

// A/C column n -> u16 offset base within a 64-row A-layout LDS tile
static __device__ __forceinline__ int colpf(int n) {
    return ((n >> 5) << 11) + (((n >> 3) & 3) << 7) + (n & 7);
}

// ---------------------------------------------------------------------------
// Prep: B-fragment-swizzled bf16 copies in d_ws (unchanged).
//   ws[0      ..65535]  : W2    as B (fwd)
//   ws[65536  ..131071] : W2^T  as B (bwd)
//   ws[131072 ..135167] : W1x^T (256x16, cols>=6 zero) as B (score GEMM)
//   ws[135168 ..143359] : W1aug (32x256: rows 0..22 = W1, 23..31 = 0) as B
// ---------------------------------------------------------------------------
__global__ void prep_swizzle(const float* __restrict__ W1, const float* __restrict__ W2,
                             unsigned short* __restrict__ ws) {
    const int g = blockIdx.x * 256 + threadIdx.x;
    unsigned short v[8];
    if (g < 8192) {
        const int l = g & 63, fid = g >> 6;
        const int kt = fid >> 4, nt = fid & 15;
        const int row0 = kt * 32 + (l >> 4) * 8;
        const int col  = nt * 16 + (l & 15);
#pragma unroll
        for (int j = 0; j < 8; ++j) v[j] = f2bf(W2[(row0 + j) * NH + col]);
        ushort4* dst = (ushort4*)(ws + (size_t)g * 8);
        dst[0] = make_ushort4(v[0], v[1], v[2], v[3]);
        dst[1] = make_ushort4(v[4], v[5], v[6], v[7]);
    } else if (g < 16384) {
        const int e = g - 8192;
        const int l = e & 63, fid = e >> 6;
        const int kt = fid >> 4, nt = fid & 15;
        const int row  = nt * 16 + (l & 15);        // W2^T[k][n] = W2[n][k]
        const int col0 = kt * 32 + (l >> 4) * 8;
#pragma unroll
        for (int j = 0; j < 8; ++j) v[j] = f2bf(W2[row * NH + col0 + j]);
        ushort4* dst = (ushort4*)(ws + 65536 + (size_t)e * 8);
        dst[0] = make_ushort4(v[0], v[1], v[2], v[3]);
        dst[1] = make_ushort4(v[4], v[5], v[6], v[7]);
    } else if (g < 16896) {
        const int e = g - 16384;
        const int l = e & 63, kt = e >> 6;
        const int n  = l & 15;
        const int k0 = kt * 32 + (l >> 4) * 8;
#pragma unroll
        for (int j = 0; j < 8; ++j)
            v[j] = (n < ND) ? f2bf(W1[(NOBS + n) * NH + k0 + j]) : (unsigned short)0;
        ushort4* dst = (ushort4*)(ws + 131072 + (size_t)e * 8);
        dst[0] = make_ushort4(v[0], v[1], v[2], v[3]);
        dst[1] = make_ushort4(v[4], v[5], v[6], v[7]);
    } else if (g < 17920) {
        const int e = g - 16896;                    // 16 frags (nt) x 64 lanes
        const int l = e & 63, nt = e >> 6;
        const int col = nt * 16 + (l & 15);
        const int r0  = (l >> 4) * 8;
#pragma unroll
        for (int j = 0; j < 8; ++j)
            v[j] = (r0 + j < NOBS + ND) ? f2bf(W1[(r0 + j) * NH + col]) : (unsigned short)0;
        ushort4* dst = (ushort4*)(ws + 135168 + (size_t)e * 8);
        dst[0] = make_ushort4(v[0], v[1], v[2], v[3]);
        dst[1] = make_ushort4(v[4], v[5], v[6], v[7]);
    }
}

// ---------------------------------------------------------------------------
// Main kernel: one WG per TWO batches (M=64 GEMMs), 256 threads = 4 waves.
// A-fragment LDS layout for 64x256 matrix M[s][c]:
//   fid = (c>>5)*4 + (s>>4); addr(u16) = fid*512 + (((c>>3)&3)*16 + (s&15))*8 + (c&7)
// Single N-pass GEMMs: 4 nt/wave, 64 AGPR accumulators, one A-sweep per GEMM.
// Biases ride in the MFMA C-operand (no epilogue adds).
// ---------------------------------------------------------------------------
__global__ __launch_bounds__(256, 4)
void svgd_kernel(const float* __restrict__ obs, const float* __restrict__ a_in,
                 const float* __restrict__ W1, const float* __restrict__ b1,
                 const float* __restrict__ W2, const float* __restrict__ b2,
                 const float* __restrict__ W3, const unsigned short* __restrict__ ws,
                 float* __restrict__ out)
{
    __shared__ __attribute__((aligned(16))) unsigned short hA[64 * NH]; // 32KB h1 -> dh2 -> masked dh1
    __shared__ float Xs[2][384];        // 3KB double-buffered X, stride 6
    __shared__ float sc_[512];          // 2KB score, stride 8
    __shared__ float med_s[2];
    // total ~37.4KB -> 4 WGs/CU

    const int t    = threadIdx.x;
    const int bb   = blockIdx.x;        // batches 2bb, 2bb+1
    const int lane = t & 63;
    const int wid  = t >> 6;
    const int w4   = wid * 4;           // this wave's first nt (GEMM N-split)
    const int quad = lane >> 4;
    const int ln15 = lane & 15;
    const int qo = t >> 7, iao = (t & 127) >> 2, jgo = t & 3;

    const unsigned short* gW2f = ws;
    const unsigned short* gW2b = ws + 65536;
    const unsigned short* gW1p = ws + 131072;
    const unsigned short* gW1f = ws + 135168;

    // ---- init: obs -> hA scratch (coalesced), X -> Xs[0] ----
    {
        float* scr = (float*)hA;
        const float* obs_g = obs + (size_t)bb * 1088;
        for (int p = t; p < 1088; p += 256) scr[p] = obs_g[p];
        const float* a_g = a_in + (size_t)bb * 384;
        for (int p = t; p < 384; p += 256) Xs[0][p] = a_g[p];
    }
    __syncthreads();
    // a0: A-fragments of [obs|X|0] (64 rows x K=32) in registers, all 4 waves
    bf16x8 a0[4];
    {
        const float* scr = (const float*)hA;
#pragma unroll
        for (int m = 0; m < 4; ++m) {
            const int s = m * 16 + ln15;
#pragma unroll
            for (int j = 0; j < 8; ++j) {
                const int k = quad * 8 + j;
                float v = 0.0f;
                if (k < NOBS) v = scr[s * NOBS + k];
                else if (k < NOBS + ND) v = Xs[0][s * 6 + (k - NOBS)];
                a0[m][j] = (__bf16)v;
            }
        }
    }
    __syncthreads();   // scr reads done before step-0 P0 writes hA

    // ---- persistent per-thread scalars (no w1b: re-read from L2 each step) ----
    float b1r[4], b2r[4]; unsigned short w3u[4];
#pragma unroll
    for (int q = 0; q < 4; ++q) {
        const int n = (w4 + q) * 16 + ln15;
        b1r[q] = b1[n]; b2r[q] = b2[n]; w3u[q] = f2bf(W3[n]);
    }

    float logp_r = 0.0f;                // owned by jgo==3 threads
    int cur = 0;
    const f32x4 zv = {0.f, 0.f, 0.f, 0.f};

    for (int step = 0; step < NSTEPS; ++step) {
        // ---- P0: h1 = relu([obs|X] @ W1aug + b1), bias in C-operand ----
        unsigned long long mask1 = 0ull;
        {
            bf16x8 w1B[4];
#pragma unroll
            for (int q = 0; q < 4; ++q)
                w1B[q] = *(const bf16x8*)(gW1f + ((w4 + q) * 64 + lane) * 8);
            f32x4 cb1[4];
#pragma unroll
            for (int q = 0; q < 4; ++q) {
                cb1[q][0] = b1r[q]; cb1[q][1] = b1r[q];
                cb1[q][2] = b1r[q]; cb1[q][3] = b1r[q];
            }
            f32x4 acc0[4][4];
#pragma unroll
            for (int m = 0; m < 4; ++m)
#pragma unroll
                for (int q = 0; q < 4; ++q) acc0[m][q] = MFMA(a0[m], w1B[q], cb1[q]);
#pragma unroll
            for (int q = 0; q < 4; ++q) {
                const int cp = colpf((w4 + q) * 16 + ln15);
#pragma unroll
                for (int m = 0; m < 4; ++m)
#pragma unroll
                    for (int reg = 0; reg < 4; ++reg) {
                        const float hv = acc0[m][q][reg];
                        const int idx = cp + m * 512 + (quad * 4 + reg) * 8;
                        if (hv > 0.f) {
                            mask1 |= 1ull << (q * 16 + m * 4 + reg);
                            hA[idx] = f2bf(hv);
                        } else hA[idx] = 0;
                    }
            }
        }
        __syncthreads();  // S1

        // ---- P2: fwd GEMM h2_pre = h1 @ W2 + b2 (bias in C-init) ----
        {
            f32x4 acc[4][4];
#pragma unroll
            for (int q = 0; q < 4; ++q) {
                f32x4 cb2;
                cb2[0] = b2r[q]; cb2[1] = b2r[q]; cb2[2] = b2r[q]; cb2[3] = b2r[q];
#pragma unroll
                for (int m = 0; m < 4; ++m) acc[m][q] = cb2;
            }
#pragma unroll 2
            for (int kt = 0; kt < 8; ++kt) {
                bf16x8 a[4];
#pragma unroll
                for (int m = 0; m < 4; ++m)
                    a[m] = *(const bf16x8*)&hA[(kt * 4 + m) * 512 + lane * 8];
#pragma unroll
                for (int q = 0; q < 4; ++q) {
                    const bf16x8 bf = *(const bf16x8*)(gW2f + ((kt * 16 + w4 + q) * 64 + lane) * 8);
#pragma unroll
                    for (int m = 0; m < 4; ++m) acc[m][q] = MFMA(a[m], bf, acc[m][q]);
                }
            }
            __syncthreads();  // S2: all h1 reads done
            // epilogue: dh2 = (h2_pre > 0) ? W3 : 0, straight from acc
#pragma unroll
            for (int q = 0; q < 4; ++q) {
                const int cp = colpf((w4 + q) * 16 + ln15);
                const unsigned short w3v = w3u[q];
#pragma unroll
                for (int m = 0; m < 4; ++m)
#pragma unroll
                    for (int reg = 0; reg < 4; ++reg) {
                        const int idx = cp + m * 512 + (quad * 4 + reg) * 8;
                        hA[idx] = (acc[m][q][reg] > 0.f) ? w3v : (unsigned short)0;
                    }
            }
        }
        __syncthreads();  // S3: dh2 visible

        // ---- P3: bwd GEMM dh1 = dh2 @ W2^T, single pass ----
        {
            f32x4 acc2[4][4];
#pragma unroll
            for (int m = 0; m < 4; ++m)
#pragma unroll
                for (int q = 0; q < 4; ++q) acc2[m][q] = zv;
#pragma unroll 2
            for (int kt = 0; kt < 8; ++kt) {
                bf16x8 a[4];
#pragma unroll
                for (int m = 0; m < 4; ++m)
                    a[m] = *(const bf16x8*)&hA[(kt * 4 + m) * 512 + lane * 8];
#pragma unroll
                for (int q = 0; q < 4; ++q) {
                    const bf16x8 bf = *(const bf16x8*)(gW2b + ((kt * 16 + w4 + q) * 64 + lane) * 8);
#pragma unroll
                    for (int m = 0; m < 4; ++m) acc2[m][q] = MFMA(a[m], bf, acc2[m][q]);
                }
            }
            __syncthreads();  // S4: all dh2 reads done
            // epilogue: masked dh1 from register bitmask
#pragma unroll
            for (int q = 0; q < 4; ++q) {
                const int cp = colpf((w4 + q) * 16 + ln15);
#pragma unroll
                for (int m = 0; m < 4; ++m)
#pragma unroll
                    for (int reg = 0; reg < 4; ++reg) {
                        const int idx = cp + m * 512 + (quad * 4 + reg) * 8;
                        hA[idx] = ((mask1 >> (q * 16 + m * 4 + reg)) & 1ull)
                                      ? f2bf(acc2[m][q][reg]) : (unsigned short)0;
                    }
            }
        }
        __syncthreads();  // S5: masked dh1 visible

        // ---- P5: waves 2,3: score GEMM; waves 0,1: exact median ----
        if (wid >= 2) {
            const int mb = (wid - 2) * 2;
            f32x4 sa[2] = {zv, zv};
#pragma unroll
            for (int kt = 0; kt < 8; ++kt) {
                const bf16x8 bw = *(const bf16x8*)(gW1p + (kt * 64 + lane) * 8);
#pragma unroll
                for (int mm = 0; mm < 2; ++mm) {
                    const bf16x8 a = *(const bf16x8*)&hA[(kt * 4 + mb + mm) * 512 + lane * 8];
                    sa[mm] = MFMA(a, bw, sa[mm]);
                }
            }
            if (ln15 < ND) {
#pragma unroll
                for (int mm = 0; mm < 2; ++mm)
#pragma unroll
                    for (int reg = 0; reg < 4; ++reg)
                        sc_[((mb + mm) * 16 + quad * 4 + reg) * 8 + ln15] = sa[mm][reg];
            }
        } else {
            // rank-239 of 496 pair dists == rank-511 of full 1024 multiset (exact).
            const float* Xc = &Xs[cur][wid * 192];
            unsigned u[8];
#pragma unroll
            for (int r = 0; r < 8; ++r) {
                const int e = lane + 64 * r;
                if (e < 496) {
                    int i = (int)((63.0f - sqrtf(3969.0f - 8.0f * (float)e)) * 0.5f);
                    while (i * (63 - i) / 2 > e) --i;
                    while ((i + 1) * (62 - i) / 2 <= e) ++i;
                    const int j = i + 1 + (e - i * (63 - i) / 2);
                    float s = 0.f;
#pragma unroll
                    for (int d = 0; d < ND; ++d) {
                        const float df = Xc[i * 6 + d] - Xc[j * 6 + d];
                        s += df * df;
                    }
                    u[r] = __float_as_uint(s);
                } else u[r] = 0x7f800000u;
            }
            unsigned P = 0u;
            for (int bit = 30; bit >= 0; --bit) {
                const unsigned Q = P | (1u << bit);
                int c = 0;
#pragma unroll
                for (int r = 0; r < 8; ++r)
                    c += __popcll(__ballot(u[r] < Q));
                if (c <= 239) P = Q;
            }
            if (lane == 0) med_s[wid] = __uint_as_float(P);
        }
        __syncthreads();  // S6

        // ---- phi/l4/l5 partials; thread (batch qo, particle iao, 8 j's) ----
        {
            const int nxt = cur ^ 1;
            const float gam = 1.0f / (1e-8f + med_s[qo] / C_LOGNP1);
            const float* Xc = &Xs[cur][qo * 192];
            float xi[6];
#pragma unroll
            for (int d = 0; d < ND; ++d) xi[d] = Xc[iao * 6 + d];
            float w[8] = {0, 0, 0, 0, 0, 0, 0, 0};
#pragma unroll
            for (int jj = 0; jj < 8; ++jj) {
                const int j = jgo * 8 + jj;
                float df6[6], sj6[6];
                float dsv = 0.f, dot = 0.f;
#pragma unroll
                for (int d = 0; d < ND; ++d) {
                    df6[d] = xi[d] - Xc[j * 6 + d];
                    sj6[d] = sc_[(qo * 32 + j) * 8 + d];
                    dsv += df6[d] * df6[d];
                    dot += df6[d] * sj6[d];
                }
                const float kap = __expf(-gam * dsv);
                const float tg = 2.0f * gam * kap;
#pragma unroll
                for (int d = 0; d < ND; ++d) w[d] += kap * sj6[d] + tg * df6[d];
                w[6] -= tg * dot;                 // line_4 partial
                w[7] += tg * dsv - 6.0f * kap;    // line_5 partial (pre -2*gamma)
            }
#pragma unroll
            for (int off = 1; off < 4; off <<= 1)
#pragma unroll
                for (int c = 0; c < 8; ++c) w[c] += __shfl_xor(w[c], off);
            // commit to Xs[nxt] (disjoint buffer: no barrier vs phi reads)
            const int base = (qo * 32 + iao) * 6;
            {
                float x = xi[jgo] + C_LR * (w[jgo] * (1.0f / 32.0f));
                Xs[nxt][base + jgo] = fminf(fmaxf(x, -C_LIM), C_LIM);
            }
            if (jgo < 2) {
                const int d = jgo + 4;
                float x = xi[d] + C_LR * (w[d] * (1.0f / 32.0f));
                Xs[nxt][base + d] = fminf(fmaxf(x, -C_LIM), C_LIM);
            }
            if (jgo == 3)
                logp_r -= C_LR * (w[6] * (1.0f / 32.0f)
                                  - 2.0f * gam * (w[7] * (1.0f / 32.0f)));
        }
        __syncthreads();  // S7: new Xs visible

        // refresh a0 X-slots (k=17..22 -> j=1..6, quad 2 lanes hold them)
        cur ^= 1;
        if (quad == 2) {
#pragma unroll
            for (int m = 0; m < 4; ++m) {
                const int s = m * 16 + ln15;
#pragma unroll
                for (int j = 1; j <= 6; ++j)
                    a0[m][j] = (__bf16)Xs[cur][s * 6 + (j - 1)];
            }
        }
    }

    // ---- output: a (B*N, D) then logp (B, N) ----
    for (int p = t; p < 384; p += 256) out[(size_t)bb * 384 + p] = Xs[cur][p];
    if (jgo == 3) out[(size_t)NB * NP * ND + bb * 64 + qo * 32 + iao] = logp_r;
}

extern "C" void kernel_launch(void* const* d_in, const int* in_sizes, int n_in,
                              void* d_out, int out_size, void* d_ws, size_t ws_size,
                              hipStream_t stream) {
    const float* obs = (const float*)d_in[0];
    const float* a   = (const float*)d_in[1];
    const float* W1  = (const float*)d_in[2];
    const float* b1  = (const float*)d_in[3];
    const float* W2  = (const float*)d_in[4];
    const float* b2  = (const float*)d_in[5];
    const float* W3  = (const float*)d_in[6];
    // d_in[7] = b3: unused (constant offset drops out of grad; q-values never output)
    unsigned short* wsu = (unsigned short*)d_ws;   // needs 286720 bytes
    float* out = (float*)d_out;

    prep_swizzle<<<70, 256, 0, stream>>>(W1, W2, wsu);
    svgd_kernel<<<NB / 2, 256, 0, stream>>>(obs, a, W1, b1, W2, b2, W3, wsu, out);
}

// Round 11
// 510.449 us; speedup vs baseline: 1.2431x; 1.0157x over previous
//
#include <hip/hip_runtime.h>
#include <hip/hip_bf16.h>

#define NB 2048      // batches
#define NP 32        // particles per batch
#define ND 6         // action dim
#define NOBS 17      // obs dim
#define NH 256       // hidden
#define NSTEPS 10
#define C_LR 0.1f
#define C_LIM 1.0f
#define C_LOGNP1 3.4965075614664802f   // float32(log(33))

typedef __bf16 bf16x8 __attribute__((ext_vector_type(8)));
typedef float  f32x4  __attribute__((ext_vector_type(4)));

#define MFMA(a, b, c) __builtin_amdgcn_mfma_f32_16x16x32_bf16(a, b, c, 0, 0, 0)

// fp32 -> bf16 bits, round-to-nearest-even (finite inputs) — pure register ops
static __device__ __forceinline__ unsigned short f2bf(float f) {
    union { float f; unsigned u; } c; c.f = f;
    const unsigned r = c.u + 0x7fffu + ((c.u >> 16) & 1u);
    return (unsigned short)(r >> 16);
}

// A/C column n -> u16 offset base within a 64-row A-layout LDS tile
static __device__ __forceinline__ int colpf(int n) {
    return ((n >> 5) << 11) + (((n >> 3) & 3) << 7) + (n & 7);
}

// ---------------------------------------------------------------------------
// Prep: B-fragment-swizzled bf16 copies in d_ws.
//   ws[0      ..65535]  : W2    as B (fwd)
//   ws[65536  ..131071] : W2^T  as B (bwd)
//   ws[131072 ..135167] : W1x^T (256x16, cols>=6 zero) as B (score GEMM)
//   ws[135168 ..143359] : W1aug (32x256: rows 0..22 = W1, row 23 = b1,
//                         rows 24..31 = 0) as B  — b1 baked into the GEMM
// ---------------------------------------------------------------------------
__global__ void prep_swizzle(const float* __restrict__ W1, const float* __restrict__ W2,
                             const float* __restrict__ b1,
                             unsigned short* __restrict__ ws) {
    const int g = blockIdx.x * 256 + threadIdx.x;
    unsigned short v[8];
    if (g < 8192) {
        const int l = g & 63, fid = g >> 6;
        const int kt = fid >> 4, nt = fid & 15;
        const int row0 = kt * 32 + (l >> 4) * 8;
        const int col  = nt * 16 + (l & 15);
#pragma unroll
        for (int j = 0; j < 8; ++j) v[j] = f2bf(W2[(row0 + j) * NH + col]);
        ushort4* dst = (ushort4*)(ws + (size_t)g * 8);
        dst[0] = make_ushort4(v[0], v[1], v[2], v[3]);
        dst[1] = make_ushort4(v[4], v[5], v[6], v[7]);
    } else if (g < 16384) {
        const int e = g - 8192;
        const int l = e & 63, fid = e >> 6;
        const int kt = fid >> 4, nt = fid & 15;
        const int row  = nt * 16 + (l & 15);        // W2^T[k][n] = W2[n][k]
        const int col0 = kt * 32 + (l >> 4) * 8;
#pragma unroll
        for (int j = 0; j < 8; ++j) v[j] = f2bf(W2[row * NH + col0 + j]);
        ushort4* dst = (ushort4*)(ws + 65536 + (size_t)e * 8);
        dst[0] = make_ushort4(v[0], v[1], v[2], v[3]);
        dst[1] = make_ushort4(v[4], v[5], v[6], v[7]);
    } else if (g < 16896) {
        const int e = g - 16384;
        const int l = e & 63, kt = e >> 6;
        const int n  = l & 15;
        const int k0 = kt * 32 + (l >> 4) * 8;
#pragma unroll
        for (int j = 0; j < 8; ++j)
            v[j] = (n < ND) ? f2bf(W1[(NOBS + n) * NH + k0 + j]) : (unsigned short)0;
        ushort4* dst = (ushort4*)(ws + 131072 + (size_t)e * 8);
        dst[0] = make_ushort4(v[0], v[1], v[2], v[3]);
        dst[1] = make_ushort4(v[4], v[5], v[6], v[7]);
    } else if (g < 17920) {
        const int e = g - 16896;                    // 16 frags (nt) x 64 lanes
        const int l = e & 63, nt = e >> 6;
        const int col = nt * 16 + (l & 15);
        const int r0  = (l >> 4) * 8;
#pragma unroll
        for (int j = 0; j < 8; ++j) {
            const int r = r0 + j;
            v[j] = (r < NOBS + ND) ? f2bf(W1[r * NH + col])
                 : (r == 23 ? f2bf(b1[col]) : (unsigned short)0);
        }
        ushort4* dst = (ushort4*)(ws + 135168 + (size_t)e * 8);
        dst[0] = make_ushort4(v[0], v[1], v[2], v[3]);
        dst[1] = make_ushort4(v[4], v[5], v[6], v[7]);
    }
}

// ---------------------------------------------------------------------------
// Main kernel: one WG per TWO batches (M=64 GEMMs), 256 threads = 4 waves.
// A-fragment LDS layout for 64x256 matrix M[s][c]:
//   fid = (c>>5)*4 + (s>>4); addr(u16) = fid*512 + (((c>>3)&3)*16 + (s&15))*8 + (c&7)
// Single N-pass GEMMs: 4 nt/wave, 64 AGPR accumulators, one A-sweep per GEMM.
// Register diet: b1 baked into W1aug (a0 k=23 carries 1.0); b2/W3 loaded
// per-step in the epilogues — GEMM-phase live set fits the 128-reg cap.
// ---------------------------------------------------------------------------
__global__ __launch_bounds__(256, 4)
void svgd_kernel(const float* __restrict__ obs, const float* __restrict__ a_in,
                 const float* __restrict__ W1, const float* __restrict__ b1,
                 const float* __restrict__ W2, const float* __restrict__ b2,
                 const float* __restrict__ W3, const unsigned short* __restrict__ ws,
                 float* __restrict__ out)
{
    __shared__ __attribute__((aligned(16))) unsigned short hA[64 * NH]; // 32KB h1 -> dh2 -> masked dh1
    __shared__ float Xs[2][384];        // 3KB double-buffered X, stride 6
    __shared__ float sc_[512];          // 2KB score, stride 8
    __shared__ float med_s[2];
    // total ~37.4KB -> 4 WGs/CU

    const int t    = threadIdx.x;
    const int bb   = blockIdx.x;        // batches 2bb, 2bb+1
    const int lane = t & 63;
    const int wid  = t >> 6;
    const int w4   = wid * 4;           // this wave's first nt (GEMM N-split)
    const int quad = lane >> 4;
    const int ln15 = lane & 15;
    const int qo = t >> 7, iao = (t & 127) >> 2, jgo = t & 3;

    const unsigned short* gW2f = ws;
    const unsigned short* gW2b = ws + 65536;
    const unsigned short* gW1p = ws + 131072;
    const unsigned short* gW1f = ws + 135168;

    // ---- init: obs -> hA scratch (coalesced), X -> Xs[0] ----
    {
        float* scr = (float*)hA;
        const float* obs_g = obs + (size_t)bb * 1088;
        for (int p = t; p < 1088; p += 256) scr[p] = obs_g[p];
        const float* a_g = a_in + (size_t)bb * 384;
        for (int p = t; p < 384; p += 256) Xs[0][p] = a_g[p];
    }
    __syncthreads();
    // a0: A-fragments of [obs|X|1|0] (64 rows x K=32) in registers, all 4 waves
    bf16x8 a0[4];
    {
        const float* scr = (const float*)hA;
#pragma unroll
        for (int m = 0; m < 4; ++m) {
            const int s = m * 16 + ln15;
#pragma unroll
            for (int j = 0; j < 8; ++j) {
                const int k = quad * 8 + j;
                float v = 0.0f;
                if (k < NOBS) v = scr[s * NOBS + k];
                else if (k < NOBS + ND) v = Xs[0][s * 6 + (k - NOBS)];
                else if (k == 23) v = 1.0f;          // bias slot (W1aug row 23 = b1)
                a0[m][j] = (__bf16)v;
            }
        }
    }
    __syncthreads();   // scr reads done before step-0 P0 writes hA

    float logp_r = 0.0f;                // owned by jgo==3 threads
    int cur = 0;
    const f32x4 zv = {0.f, 0.f, 0.f, 0.f};

    for (int step = 0; step < NSTEPS; ++step) {
        // ---- P0: h1 = relu([obs|X|1] @ W1aug) via K=32 MFMA (b1 baked in B) ----
        unsigned long long mask1 = 0ull;
        {
            bf16x8 w1B[4];
#pragma unroll
            for (int q = 0; q < 4; ++q)
                w1B[q] = *(const bf16x8*)(gW1f + ((w4 + q) * 64 + lane) * 8);
            f32x4 acc0[4][4];
#pragma unroll
            for (int m = 0; m < 4; ++m)
#pragma unroll
                for (int q = 0; q < 4; ++q) acc0[m][q] = MFMA(a0[m], w1B[q], zv);
#pragma unroll
            for (int q = 0; q < 4; ++q) {
                const int cp = colpf((w4 + q) * 16 + ln15);
#pragma unroll
                for (int m = 0; m < 4; ++m)
#pragma unroll
                    for (int reg = 0; reg < 4; ++reg) {
                        const float hv = acc0[m][q][reg];
                        const int idx = cp + m * 512 + (quad * 4 + reg) * 8;
                        if (hv > 0.f) {
                            mask1 |= 1ull << (q * 16 + m * 4 + reg);
                            hA[idx] = f2bf(hv);
                        } else hA[idx] = 0;
                    }
            }
        }
        __syncthreads();  // S1

        // ---- P2: fwd GEMM h2_pre = h1 @ W2, single pass ----
        {
            f32x4 acc[4][4];
#pragma unroll
            for (int m = 0; m < 4; ++m)
#pragma unroll
                for (int q = 0; q < 4; ++q) acc[m][q] = zv;
#pragma unroll 2
            for (int kt = 0; kt < 8; ++kt) {
                bf16x8 a[4];
#pragma unroll
                for (int m = 0; m < 4; ++m)
                    a[m] = *(const bf16x8*)&hA[(kt * 4 + m) * 512 + lane * 8];
#pragma unroll
                for (int q = 0; q < 4; ++q) {
                    const bf16x8 bf = *(const bf16x8*)(gW2f + ((kt * 16 + w4 + q) * 64 + lane) * 8);
#pragma unroll
                    for (int m = 0; m < 4; ++m) acc[m][q] = MFMA(a[m], bf, acc[m][q]);
                }
            }
            __syncthreads();  // S2: all h1 reads done
            // epilogue: dh2 = (h2_pre + b2 > 0) ? W3 : 0  (b2/W3 loaded per step)
#pragma unroll
            for (int q = 0; q < 4; ++q) {
                const int n = (w4 + q) * 16 + ln15;
                const int cp = colpf(n);
                const float b2v = b2[n];
                const unsigned short w3v = f2bf(W3[n]);
#pragma unroll
                for (int m = 0; m < 4; ++m)
#pragma unroll
                    for (int reg = 0; reg < 4; ++reg) {
                        const int idx = cp + m * 512 + (quad * 4 + reg) * 8;
                        hA[idx] = (acc[m][q][reg] + b2v > 0.f) ? w3v : (unsigned short)0;
                    }
            }
        }
        __syncthreads();  // S3: dh2 visible

        // ---- P3: bwd GEMM dh1 = dh2 @ W2^T, single pass ----
        {
            f32x4 acc2[4][4];
#pragma unroll
            for (int m = 0; m < 4; ++m)
#pragma unroll
                for (int q = 0; q < 4; ++q) acc2[m][q] = zv;
#pragma unroll 2
            for (int kt = 0; kt < 8; ++kt) {
                bf16x8 a[4];
#pragma unroll
                for (int m = 0; m < 4; ++m)
                    a[m] = *(const bf16x8*)&hA[(kt * 4 + m) * 512 + lane * 8];
#pragma unroll
                for (int q = 0; q < 4; ++q) {
                    const bf16x8 bf = *(const bf16x8*)(gW2b + ((kt * 16 + w4 + q) * 64 + lane) * 8);
#pragma unroll
                    for (int m = 0; m < 4; ++m) acc2[m][q] = MFMA(a[m], bf, acc2[m][q]);
                }
            }
            __syncthreads();  // S4: all dh2 reads done
            // epilogue: masked dh1 from register bitmask
#pragma unroll
            for (int q = 0; q < 4; ++q) {
                const int cp = colpf((w4 + q) * 16 + ln15);
#pragma unroll
                for (int m = 0; m < 4; ++m)
#pragma unroll
                    for (int reg = 0; reg < 4; ++reg) {
                        const int idx = cp + m * 512 + (quad * 4 + reg) * 8;
                        hA[idx] = ((mask1 >> (q * 16 + m * 4 + reg)) & 1ull)
                                      ? f2bf(acc2[m][q][reg]) : (unsigned short)0;
                    }
            }
        }
        __syncthreads();  // S5: masked dh1 visible

        // ---- P5: waves 2,3: score GEMM; waves 0,1: exact median ----
        if (wid >= 2) {
            const int mb = (wid - 2) * 2;
            f32x4 sa[2] = {zv, zv};
#pragma unroll
            for (int kt = 0; kt < 8; ++kt) {
                const bf16x8 bw = *(const bf16x8*)(gW1p + (kt * 64 + lane) * 8);
#pragma unroll
                for (int mm = 0; mm < 2; ++mm) {
                    const bf16x8 a = *(const bf16x8*)&hA[(kt * 4 + mb + mm) * 512 + lane * 8];
                    sa[mm] = MFMA(a, bw, sa[mm]);
                }
            }
            if (ln15 < ND) {
#pragma unroll
                for (int mm = 0; mm < 2; ++mm)
#pragma unroll
                    for (int reg = 0; reg < 4; ++reg)
                        sc_[((mb + mm) * 16 + quad * 4 + reg) * 8 + ln15] = sa[mm][reg];
            }
        } else {
            // rank-239 of 496 pair dists == rank-511 of full 1024 multiset (exact).
            const float* Xc = &Xs[cur][wid * 192];
            unsigned u[8];
#pragma unroll
            for (int r = 0; r < 8; ++r) {
                const int e = lane + 64 * r;
                if (e < 496) {
                    int i = (int)((63.0f - sqrtf(3969.0f - 8.0f * (float)e)) * 0.5f);
                    while (i * (63 - i) / 2 > e) --i;
                    while ((i + 1) * (62 - i) / 2 <= e) ++i;
                    const int j = i + 1 + (e - i * (63 - i) / 2);
                    float s = 0.f;
#pragma unroll
                    for (int d = 0; d < ND; ++d) {
                        const float df = Xc[i * 6 + d] - Xc[j * 6 + d];
                        s += df * df;
                    }
                    u[r] = __float_as_uint(s);
                } else u[r] = 0x7f800000u;
            }
            unsigned P = 0u;
            for (int bit = 30; bit >= 0; --bit) {
                const unsigned Q = P | (1u << bit);
                int c = 0;
#pragma unroll
                for (int r = 0; r < 8; ++r)
                    c += __popcll(__ballot(u[r] < Q));
                if (c <= 239) P = Q;
            }
            if (lane == 0) med_s[wid] = __uint_as_float(P);
        }
        __syncthreads();  // S6

        // ---- phi/l4/l5 partials; thread (batch qo, particle iao, 8 j's) ----
        {
            const int nxt = cur ^ 1;
            const float gam = 1.0f / (1e-8f + med_s[qo] / C_LOGNP1);
            const float* Xc = &Xs[cur][qo * 192];
            float xi[6];
#pragma unroll
            for (int d = 0; d < ND; ++d) xi[d] = Xc[iao * 6 + d];
            float w[8] = {0, 0, 0, 0, 0, 0, 0, 0};
#pragma unroll
            for (int jj = 0; jj < 8; ++jj) {
                const int j = jgo * 8 + jj;
                float df6[6], sj6[6];
                float dsv = 0.f, dot = 0.f;
#pragma unroll
                for (int d = 0; d < ND; ++d) {
                    df6[d] = xi[d] - Xc[j * 6 + d];
                    sj6[d] = sc_[(qo * 32 + j) * 8 + d];
                    dsv += df6[d] * df6[d];
                    dot += df6[d] * sj6[d];
                }
                const float kap = __expf(-gam * dsv);
                const float tg = 2.0f * gam * kap;
#pragma unroll
                for (int d = 0; d < ND; ++d) w[d] += kap * sj6[d] + tg * df6[d];
                w[6] -= tg * dot;                 // line_4 partial
                w[7] += tg * dsv - 6.0f * kap;    // line_5 partial (pre -2*gamma)
            }
#pragma unroll
            for (int off = 1; off < 4; off <<= 1)
#pragma unroll
                for (int c = 0; c < 8; ++c) w[c] += __shfl_xor(w[c], off);
            // commit to Xs[nxt] (disjoint buffer: no barrier vs phi reads)
            const int base = (qo * 32 + iao) * 6;
            {
                float x = xi[jgo] + C_LR * (w[jgo] * (1.0f / 32.0f));
                Xs[nxt][base + jgo] = fminf(fmaxf(x, -C_LIM), C_LIM);
            }
            if (jgo < 2) {
                const int d = jgo + 4;
                float x = xi[d] + C_LR * (w[d] * (1.0f / 32.0f));
                Xs[nxt][base + d] = fminf(fmaxf(x, -C_LIM), C_LIM);
            }
            if (jgo == 3)
                logp_r -= C_LR * (w[6] * (1.0f / 32.0f)
                                  - 2.0f * gam * (w[7] * (1.0f / 32.0f)));
        }
        __syncthreads();  // S7: new Xs visible

        // refresh a0 X-slots (k=17..22 -> j=1..6, quad 2 lanes hold them; j=7 is the 1.0 slot)
        cur ^= 1;
        if (quad == 2) {
#pragma unroll
            for (int m = 0; m < 4; ++m) {
                const int s = m * 16 + ln15;
#pragma unroll
                for (int j = 1; j <= 6; ++j)
                    a0[m][j] = (__bf16)Xs[cur][s * 6 + (j - 1)];
            }
        }
    }

    // ---- output: a (B*N, D) then logp (B, N) ----
    for (int p = t; p < 384; p += 256) out[(size_t)bb * 384 + p] = Xs[cur][p];
    if (jgo == 3) out[(size_t)NB * NP * ND + bb * 64 + qo * 32 + iao] = logp_r;
}

extern "C" void kernel_launch(void* const* d_in, const int* in_sizes, int n_in,
                              void* d_out, int out_size, void* d_ws, size_t ws_size,
                              hipStream_t stream) {
    const float* obs = (const float*)d_in[0];
    const float* a   = (const float*)d_in[1];
    const float* W1  = (const float*)d_in[2];
    const float* b1  = (const float*)d_in[3];
    const float* W2  = (const float*)d_in[4];
    const float* b2  = (const float*)d_in[5];
    const float* W3  = (const float*)d_in[6];
    // d_in[7] = b3: unused (constant offset drops out of grad; q-values never output)
    unsigned short* wsu = (unsigned short*)d_ws;   // needs 286720 bytes
    float* out = (float*)d_out;

    prep_swizzle<<<70, 256, 0, stream>>>(W1, W2, b1, wsu);
    svgd_kernel<<<NB / 2, 256, 0, stream>>>(obs, a, W1, b1, W2, b2, W3, wsu, out);
}